// Round 5
// baseline (423.967 us; speedup 1.0000x reference)
//
#include <hip/hip_runtime.h>
#include <hip/hip_bf16.h>

#define TT 512
#define DD 512
#define VV 2048
#define HH 128

typedef __attribute__((ext_vector_type(8))) short bf16x8;
typedef __attribute__((ext_vector_type(8))) unsigned short ushort8;
typedef __attribute__((ext_vector_type(4))) unsigned short ushort4v;
typedef __attribute__((ext_vector_type(4))) float f32x4;

__device__ __forceinline__ unsigned short f2bf(float f) {
  union { __hip_bfloat16 b; unsigned short u; } cv;
  cv.b = __float2bfloat16(f);
  return cv.u;
}

// LDS-only barrier: orders ds ops across waves without draining vmcnt.
__device__ __forceinline__ void lds_barrier() {
  asm volatile("s_waitcnt lgkmcnt(0)\n\ts_barrier" ::: "memory");
}

__global__ void cvt_x_kernel(const float* __restrict__ x, unsigned short* __restrict__ xb) {
  const int i = blockIdx.x * blockDim.x + threadIdx.x;
  const float4 f = ((const float4*)x)[i];
  ushort4v u;
  u[0] = f2bf(f.x); u[1] = f2bf(f.y); u[2] = f2bf(f.z); u[3] = f2bf(f.w);
  ((ushort4v*)xb)[i] = u;
}

// 4 WGs per voxel (128 t-rows each), 512 thr = 8 waves in a 4row x 2col grid:
// wave (wr,wc) computes rows [rowbase+wr*32,+32) x cols [wc*64,+64) in layer 1.
// Col-split halves per-wave LDS B-reads (the measured pole). BK=64 halves barriers.
// LDS map (64 KiB):
//   [0, 32768)      : W2[v] bf16, fragment-linear in PERMUTED k' order, 4 x 8 KiB
//   [32768, 65536)  : W1 ring 2 x 16 KiB (2 x 8 KiB k-subtiles each)   (phase A)
//   [32768, 65536)  : h1 band 128 rows x 256 B (k'-ordered, swizzled)  (phase B)
// k' permutation: layer-1 col h = wc*64+n*16+ll  <->  k' = ll*8+wc*4+n, so each
// lane's 4 h1 values are byte-contiguous (one ds_write_b64) and layer-2 A-frags
// are one ds_read_b128; W2 is staged with rows in the same k' order.
__global__ __launch_bounds__(512, 4)
void voxel_mlp_kernel(const unsigned short* __restrict__ Xb,
                      const float* __restrict__ W1,
                      const float* __restrict__ b1,
                      const float* __restrict__ W2,
                      const float* __restrict__ b2,
                      const float* __restrict__ W3,
                      const float* __restrict__ b3,
                      float* __restrict__ out) {
  __shared__ __align__(16) char LDS[65536];
  constexpr unsigned W2BASE = 0;
  constexpr unsigned R1     = 32768;
  constexpr unsigned H1BASE = 32768;

  const int bid = blockIdx.x;
  const int xcd = bid & 7;
  const int g   = bid >> 3;
  const int v   = (g >> 2) * 8 + xcd;   // 4 quads of a voxel share an XCD's L2
  const int q   = g & 3;
  const int rowbase = q * 128;

  const int tid = threadIdx.x;
  const int w   = tid >> 6;
  const int l   = tid & 63;
  const int lg  = l >> 4;
  const int ll  = l & 15;
  const int wc  = w & 1;
  const int wr  = w >> 1;

  const float* W1v = W1 + (size_t)v * DD * HH;
  const float* W2v = W2 + (size_t)v * HH * HH;

  // W1 staging source offset (k-row lg*8+j, col w*16+ll) within a 32-row subtile
  const int stago = (lg * 8) * HH + w * 16 + ll;
  // phase-A A-frag bases: rows rowbase + wr*32 + mi*16 + ll
  const unsigned short* Xrow0 = Xb + (size_t)(rowbase + wr * 32 + ll) * DD + lg * 8;
  const unsigned short* Xrow1 = Xrow0 + 16 * DD;

  float w1s[2][2][8];   // [ring slot][k-subtile u][j]
  float w2s[8];         // single-slot W2 staging
  bf16x8 aS[2][2];      // [u][mi]

#define ISSUE_W1(t)                                                     \
  { const float* gp = W1v + stago + (t) * 64 * HH;                      \
    _Pragma("unroll") for (int u = 0; u < 2; ++u)                       \
      _Pragma("unroll") for (int j = 0; j < 8; ++j)                     \
        w1s[(t) & 1][u][j] = gp[u * 32 * HH + j * HH]; }

#define CVT_W1(t)                                                       \
  { _Pragma("unroll") for (int u = 0; u < 2; ++u) {                     \
      ushort8 uu;                                                       \
      _Pragma("unroll") for (int j = 0; j < 8; ++j)                     \
        uu[j] = f2bf(w1s[(t) & 1][u][j]);                               \
      *(ushort8*)(&LDS[R1 + (unsigned)((t) & 1) * 16384u +              \
                       (unsigned)u * 8192u + (unsigned)w * 1024u +      \
                       (unsigned)l * 16u]) = uu; } }

// W2 staged in k' order: frag elem j holds W2[row][col] with
// row = (j>>2)*64 + (j&3)*16 + t*4 + lg, col = w*16 + ll.
#define ISSUE_W2(t)                                                     \
  { const float* gp = W2v + ((t) * 4 + lg) * HH + w * 16 + ll;          \
    _Pragma("unroll") for (int j = 0; j < 8; ++j)                       \
      w2s[j] = gp[((j >> 2) * 64 + (j & 3) * 16) * HH]; }

#define CVT_W2(t)                                                       \
  { ushort8 uu;                                                         \
    _Pragma("unroll") for (int j = 0; j < 8; ++j)                       \
      uu[j] = f2bf(w2s[j]);                                             \
    *(ushort8*)(&LDS[W2BASE + (unsigned)(t) * 8192u +                   \
                     (unsigned)w * 1024u + (unsigned)l * 16u]) = uu; }

#define ISSUE_A(s)                                                      \
  { _Pragma("unroll") for (int u = 0; u < 2; ++u) {                     \
      aS[u][0] = *(const bf16x8*)(Xrow0 + (s) * 64 + u * 32);           \
      aS[u][1] = *(const bf16x8*)(Xrow1 + (s) * 64 + u * 32); } }

  // ---- prologue: tiles 0,1 to regs; tile 0 to ring slot 0 ----
  ISSUE_W1(0);
  ISSUE_W1(1);
  CVT_W1(0);            // waits tile-0 loads only; tile 1 stays in flight
  lds_barrier();

  f32x4 acc1[2][4];
#pragma unroll
  for (int mi = 0; mi < 2; ++mi)
#pragma unroll
    for (int n = 0; n < 4; ++n) acc1[mi][n] = f32x4{0.f, 0.f, 0.f, 0.f};

  // ---- phase A: layer 1, K over D in 8 steps of 64 ----
#pragma unroll
  for (int s = 0; s < 8; ++s) {
    ISSUE_A(s);                       // oldest this step: MFMA wait retires only these
    if (s + 2 < 8) ISSUE_W1(s + 2);
    if (s >= 1 && s <= 4) CVT_W2(s - 1);   // reads 1-step-old loads (retired)
    if (s < 4) ISSUE_W2(s);

#pragma unroll
    for (int u = 0; u < 2; ++u) {
#pragma unroll
      for (int n = 0; n < 4; ++n) {
        const bf16x8 b = *(const bf16x8*)(&LDS[R1 + (unsigned)(s & 1) * 16384u +
                                               (unsigned)u * 8192u +
                                               (unsigned)(wc * 4 + n) * 1024u +
                                               (unsigned)l * 16u]);
#pragma unroll
        for (int mi = 0; mi < 2; ++mi)
          acc1[mi][n] = __builtin_amdgcn_mfma_f32_16x16x32_bf16(aS[u][mi], b, acc1[mi][n], 0, 0, 0);
      }
    }

    if (s < 7) CVT_W1(s + 1);         // 2-step-old loads; leaves s+2 in flight
    lds_barrier();
  }

#undef ISSUE_W1
#undef ISSUE_W2
#undef ISSUE_A
#undef CVT_W1
#undef CVT_W2

  // biases / head weights (fp32, exact)
  float b1v[4], b2v[8], w3v[8];
#pragma unroll
  for (int n = 0; n < 4; ++n) b1v[n] = b1[v * HH + wc * 64 + n * 16 + ll];
#pragma unroll
  for (int m = 0; m < 8; ++m) {
    b2v[m] = b2[v * HH + m * 16 + ll];
    w3v[m] = W3[v * HH + m * 16 + ll];
  }
  const float b3v = b3[v];

  // ---- phase B: h1 -> LDS (k'-ordered, swizzled), then layers 2+3 ----
#pragma unroll
  for (int mi = 0; mi < 2; ++mi) {
#pragma unroll
    for (int r = 0; r < 4; ++r) {
      const int tl = wr * 32 + mi * 16 + lg * 4 + r;   // row within 128-band
      ushort4v hv;
#pragma unroll
      for (int n = 0; n < 4; ++n)
        hv[n] = f2bf(fmaxf(acc1[mi][n][r] + b1v[n], 0.f));
      const unsigned byte = H1BASE + (unsigned)tl * 256u +
                            (unsigned)((ll * 16 + wc * 8) ^ ((tl & 7) << 4));
      *(ushort4v*)(&LDS[byte]) = hv;                   // one ds_write_b64
    }
  }
  lds_barrier();

  // layer 2: wave owns rows w*16..+16 of the band
  f32x4 acc2[8];
#pragma unroll
  for (int m = 0; m < 8; ++m) acc2[m] = f32x4{0.f, 0.f, 0.f, 0.f};
  const int trow = w * 16 + ll;
#pragma unroll
  for (int ki = 0; ki < 4; ++ki) {
    const unsigned abyte = H1BASE + (unsigned)trow * 256u +
                           (unsigned)((ki * 64 + lg * 16) ^ ((ll & 7) << 4));
    const bf16x8 a2 = *(const bf16x8*)(&LDS[abyte]);
#pragma unroll
    for (int m = 0; m < 8; ++m) {
      const bf16x8 bw = *(const bf16x8*)(&LDS[W2BASE + (unsigned)ki * 8192u +
                                              (unsigned)m * 1024u + (unsigned)l * 16u]);
      acc2[m] = __builtin_amdgcn_mfma_f32_16x16x32_bf16(a2, bw, acc2[m], 0, 0, 0);
    }
  }
  // layer 3 (fp32): relu(acc2+b2) . w3, 16-lane butterfly, lane 0 writes
#pragma unroll
  for (int r = 0; r < 4; ++r) {
    float p = 0.f;
#pragma unroll
    for (int m = 0; m < 8; ++m)
      p += fmaxf(acc2[m][r] + b2v[m], 0.f) * w3v[m];
    p += __shfl_xor(p, 1);
    p += __shfl_xor(p, 2);
    p += __shfl_xor(p, 4);
    p += __shfl_xor(p, 8);
    if (ll == 0) {
      const int t = rowbase + w * 16 + lg * 4 + r;
      out[t * VV + v] = p + b3v;
    }
  }
}

extern "C" void kernel_launch(void* const* d_in, const int* in_sizes, int n_in,
                              void* d_out, int out_size, void* d_ws, size_t ws_size,
                              hipStream_t stream) {
  const float* X  = (const float*)d_in[0];
  const float* W1 = (const float*)d_in[1];
  const float* b1 = (const float*)d_in[2];
  const float* W2 = (const float*)d_in[3];
  const float* b2 = (const float*)d_in[4];
  const float* W3 = (const float*)d_in[5];
  const float* b3 = (const float*)d_in[6];
  float* out = (float*)d_out;

  unsigned short* Xb = (unsigned short*)d_ws;   // 512 KiB bf16 X

  cvt_x_kernel<<<256, 256, 0, stream>>>(X, Xb);
  voxel_mlp_kernel<<<VV * 4, 512, 0, stream>>>(Xb, W1, b1, W2, b2, W3, b3, out);
}

// Round 6
// 305.584 us; speedup vs baseline: 1.3874x; 1.3874x over previous
//
#include <hip/hip_runtime.h>
#include <hip/hip_bf16.h>

#define TT 512
#define DD 512
#define VV 2048
#define HH 128

typedef __attribute__((ext_vector_type(8))) short bf16x8;
typedef __attribute__((ext_vector_type(8))) unsigned short ushort8;
typedef __attribute__((ext_vector_type(4))) unsigned short ushort4v;
typedef __attribute__((ext_vector_type(4))) float f32x4;

__device__ __forceinline__ unsigned short f2bf(float f) {
  union { __hip_bfloat16 b; unsigned short u; } cv;
  cv.b = __float2bfloat16(f);
  return cv.u;
}

// LDS-only barrier: orders ds ops across waves without draining vmcnt,
// so global prefetches stay in flight across the barrier.
__device__ __forceinline__ void lds_barrier() {
  asm volatile("s_waitcnt lgkmcnt(0)\n\ts_barrier" ::: "memory");
}

__global__ void cvt_x_kernel(const float* __restrict__ x, unsigned short* __restrict__ xb) {
  const int i = blockIdx.x * blockDim.x + threadIdx.x;
  const float4 f = ((const float4*)x)[i];
  ushort4v u;
  u[0] = f2bf(f.x); u[1] = f2bf(f.y); u[2] = f2bf(f.z); u[3] = f2bf(f.w);
  ((ushort4v*)xb)[i] = u;
}

// One WG per voxel; 512 thr = 8 waves; wave w owns t-rows [w*64, +64).
// Staging is fully line-coalesced: wave w loads rows {tile + w*8 + j} as
// float2 per lane (cols 2l, 2l+1) -> each load instr = 512 B contiguous.
// Frag-linear LDS slots, XOR-swizzled by n-block so writes are conflict-free:
//   W1: byte = R1 + (t&1)*16K + (w>>2)*8K + n*1K + ((krun*256 + cl*16) ^ ((n&7)<<4))
//       (krun = w&3 on write / lg on read; cl = col&15)
//   W2: same with u2-block s, half-slot (w&1)*8.
// LDS map (64 KiB):
//   [0, 32768)      : W2[v] bf16 frag-linear, 4 k-tiles of 8 KiB
//   [32768, 65536)  : W1 ring 2 x 16 KiB (phase A) / h1 8 x 4 KiB (phase B)
__global__ __launch_bounds__(512, 2)
void voxel_mlp_kernel(const unsigned short* __restrict__ Xb,
                      const float* __restrict__ W1,
                      const float* __restrict__ b1,
                      const float* __restrict__ W2,
                      const float* __restrict__ b2,
                      const float* __restrict__ W3,
                      const float* __restrict__ b3,
                      float* __restrict__ out) {
  __shared__ __align__(16) char LDS[65536];
  constexpr unsigned W2BASE = 0;
  constexpr unsigned R1     = 32768;
  constexpr unsigned H1BASE = 32768;

  const int v   = blockIdx.x;
  const int tid = threadIdx.x;
  const int w   = tid >> 6;
  const int l   = tid & 63;
  const int lg  = l >> 4;
  const int ll  = l & 15;

  const float* W1v = W1 + (size_t)v * DD * HH;
  const float* W2v = W2 + (size_t)v * HH * HH;

  // writer-side slot constants (col c = 2l -> n-block, offsets)
  const int      cn    = (l >> 3) & 7;
  const unsigned xorv  = (unsigned)(cn & 7) << 4;
  const unsigned wsl1  = (unsigned)(w >> 2) * 8192u + (unsigned)cn * 1024u;
  const unsigned woff1 = ((unsigned)((w & 3) * 256 + (l & 7) * 32)) ^ xorv;
  const unsigned wsl2  = (unsigned)cn * 1024u;
  const unsigned woff2 = ((unsigned)((w >> 1) * 256 + (l & 7) * 32 + (w & 1) * 8)) ^ xorv;

  float2 w1s[2][8];   // [tile&1][row j]   (rows w*8+j of the 64-row tile)
  float2 w2s[2][4];   // [s&1][row j]      (rows s*32 + w*4 + j)

#define ISSUE_W1(t)                                                        \
  { const float* gp = W1v + ((t) * 64 + w * 8) * HH + 2 * l;               \
    _Pragma("unroll") for (int j = 0; j < 8; ++j)                          \
      w1s[(t) & 1][j] = *(const float2*)(gp + j * HH); }

#define CVT_W1(t)                                                          \
  { ushort8 e0, e1;                                                        \
    _Pragma("unroll") for (int j = 0; j < 8; ++j) {                        \
      e0[j] = f2bf(w1s[(t) & 1][j].x);                                     \
      e1[j] = f2bf(w1s[(t) & 1][j].y); }                                   \
    const unsigned b_ = R1 + (unsigned)((t) & 1) * 16384u + wsl1;          \
    *(ushort8*)(&LDS[b_ + woff1]) = e0;                                    \
    *(ushort8*)(&LDS[b_ + (woff1 ^ 16u)]) = e1; }

#define ISSUE_W2(s)                                                        \
  { const float* gp = W2v + ((s) * 32 + w * 4) * HH + 2 * l;               \
    _Pragma("unroll") for (int j = 0; j < 4; ++j)                          \
      w2s[(s) & 1][j] = *(const float2*)(gp + j * HH); }

#define CVT_W2(s)                                                          \
  { ushort4v e0, e1;                                                       \
    _Pragma("unroll") for (int j = 0; j < 4; ++j) {                        \
      e0[j] = f2bf(w2s[(s) & 1][j].x);                                     \
      e1[j] = f2bf(w2s[(s) & 1][j].y); }                                   \
    const unsigned b_ = W2BASE + (unsigned)(s) * 8192u + wsl2;             \
    *(ushort4v*)(&LDS[b_ + woff2]) = e0;                                   \
    *(ushort4v*)(&LDS[b_ + (woff2 ^ 16u)]) = e1; }

  // ---- prologue: tiles 0,1 to regs; tile 0 to ring slot 0 ----
  ISSUE_W1(0);
  ISSUE_W1(1);
  CVT_W1(0);          // waits tile-0 loads only; tile-1 stays in flight
  lds_barrier();

  f32x4 acc1[4][8];
#pragma unroll
  for (int mi = 0; mi < 4; ++mi)
#pragma unroll
    for (int n = 0; n < 8; ++n) acc1[mi][n] = f32x4{0.f, 0.f, 0.f, 0.f};

  // ---- phase A: layer 1, K over D in 8 steps of 64 ----
#pragma unroll
  for (int s = 0; s < 8; ++s) {
    // A-frags (L2-resident Xb), issued first = oldest vm ops of this step
    bf16x8 aS[2][4];
#pragma unroll
    for (int u = 0; u < 2; ++u)
#pragma unroll
      for (int mi = 0; mi < 4; ++mi)
        aS[u][mi] = *(const bf16x8*)(Xb + (size_t)(w * 64 + mi * 16 + ll) * DD +
                                     s * 64 + u * 32 + lg * 8);

    if (s + 2 < 8) ISSUE_W1(s + 2);
    if (s < 4)     ISSUE_W2(s);

    // 64 MFMAs on ring slot s&1 (b-reads: contiguous b128 per (u,n), uniform XOR)
#pragma unroll
    for (int u = 0; u < 2; ++u)
#pragma unroll
      for (int n = 0; n < 8; ++n) {
        const bf16x8 b = *(const bf16x8*)(&LDS[R1 + (unsigned)(s & 1) * 16384u +
                                               (unsigned)u * 8192u + (unsigned)n * 1024u +
                                               (((unsigned)l * 16u) ^ ((unsigned)(n & 7) << 4))]);
#pragma unroll
        for (int mi = 0; mi < 4; ++mi)
          acc1[mi][n] = __builtin_amdgcn_mfma_f32_16x16x32_bf16(aS[u][mi], b, acc1[mi][n], 0, 0, 0);
      }

    // converts read step-(s-1) loads; counted vmcnt waits leave W1(s+2), W2(s) in flight
    if (s < 7)            CVT_W1(s + 1);
    if (s >= 1 && s <= 4) CVT_W2(s - 1);
    lds_barrier();
  }

#undef ISSUE_W1
#undef ISSUE_W2
#undef CVT_W1
#undef CVT_W2

  // biases / head weights (fp32, exact)
  float b1v[8], b2v[8], w3v[8];
#pragma unroll
  for (int n = 0; n < 8; ++n) {
    b1v[n] = b1[v * HH + n * 16 + ll];
    b2v[n] = b2[v * HH + n * 16 + ll];
    w3v[n] = W3[v * HH + n * 16 + ll];
  }
  const float b3v = b3[v];

  const unsigned slot = H1BASE + (unsigned)w * 4096u;  // wave-private 16x128 bf16

  // ---- phase B: layers 2+3, per 16-row block (wave-private, no barriers) ----
#pragma unroll
  for (int mi = 0; mi < 4; ++mi) {
#pragma unroll
    for (int n = 0; n < 8; ++n) {
#pragma unroll
      for (int r = 0; r < 4; ++r) {
        const int tl = lg * 4 + r;
        float hv = acc1[mi][n][r] + b1v[n];
        hv = fmaxf(hv, 0.f);
        const int h = n * 16 + ll;
        const unsigned byte = slot + (unsigned)tl * 256u +
                              (unsigned)((h * 2) ^ ((tl & 7) << 4));
        *(unsigned short*)(&LDS[byte]) = f2bf(hv);
      }
    }
    f32x4 acc2[8];
#pragma unroll
    for (int m = 0; m < 8; ++m) acc2[m] = f32x4{0.f, 0.f, 0.f, 0.f};
#pragma unroll
    for (int ki = 0; ki < 4; ++ki) {
      const int k0 = ki * 32 + lg * 8;
      const unsigned abyte = slot + (unsigned)ll * 256u +
                             (unsigned)((k0 * 2) ^ ((ll & 7) << 4));
      const bf16x8 a2 = *(const bf16x8*)(&LDS[abyte]);
#pragma unroll
      for (int m = 0; m < 8; ++m) {
        const bf16x8 bw = *(const bf16x8*)(&LDS[W2BASE + (unsigned)ki * 8192u +
                                                (unsigned)m * 1024u +
                                                (((unsigned)l * 16u) ^ ((unsigned)(m & 7) << 4))]);
        acc2[m] = __builtin_amdgcn_mfma_f32_16x16x32_bf16(a2, bw, acc2[m], 0, 0, 0);
      }
    }
#pragma unroll
    for (int r = 0; r < 4; ++r) {
      float p = 0.f;
#pragma unroll
      for (int m = 0; m < 8; ++m)
        p += fmaxf(acc2[m][r] + b2v[m], 0.f) * w3v[m];
      p += __shfl_xor(p, 1);
      p += __shfl_xor(p, 2);
      p += __shfl_xor(p, 4);
      p += __shfl_xor(p, 8);
      if (ll == 0) {
        const int t = w * 64 + mi * 16 + lg * 4 + r;
        out[t * VV + v] = p + b3v;
      }
    }
  }
}

extern "C" void kernel_launch(void* const* d_in, const int* in_sizes, int n_in,
                              void* d_out, int out_size, void* d_ws, size_t ws_size,
                              hipStream_t stream) {
  const float* X  = (const float*)d_in[0];
  const float* W1 = (const float*)d_in[1];
  const float* b1 = (const float*)d_in[2];
  const float* W2 = (const float*)d_in[3];
  const float* b2 = (const float*)d_in[4];
  const float* W3 = (const float*)d_in[5];
  const float* b3 = (const float*)d_in[6];
  float* out = (float*)d_out;

  unsigned short* Xb = (unsigned short*)d_ws;   // 512 KiB bf16 X

  cvt_x_kernel<<<256, 256, 0, stream>>>(X, Xb);
  voxel_mlp_kernel<<<VV, 512, 0, stream>>>(Xb, W1, b1, W2, b2, W3, b3, out);
}